// Round 6
// baseline (113.242 us; speedup 1.0000x reference)
//
#include <hip/hip_runtime.h>

// AbsolutePositionExtractor: features[b, s*4 + {0..3}] =
//   [sin(rad_lat*2^s), cos(rad_lat*2^s), sin(rad_lon*2^s), cos(rad_lon*2^s)]
// rad = fl32(deg * fl32(pi/180)); scale_s = int32(2**s) -> JAX int32 wrap:
// s=31 -> -2^31 (sign flip), s>=32 -> 0 -> (sin,cos)=(0,1). mask+positions = 0.
//
// Streaming-store bound (~524 MB). Mapping u -> (b=u>>6, s=u&63): consecutive
// lanes write consecutive float4s, so EVERY store instruction is a fully
// contiguous 1 KB wave burst (same pattern as the 87%-peak harness fill).
// Branchless: all lanes run the uniform f64 reduction + HW trig; s>=32 lanes
// select (0,1,0,1), s==31 sign-flips via select. NT stores (R3 fastest w/ NT).

typedef float f32x4 __attribute__((ext_vector_type(4)));

__global__ __launch_bounds__(256) void posfeat_kernel(const float* __restrict__ ll,
                                                      f32x4* __restrict__ out,
                                                      int B, long long n4) {
    const double QHI = 0x1.45F306DC9C883p-3;      // fl64(1/(2*pi))
    const float DEG2RAD = 0.017453292519943295f;  // fl32(pi/180), matches np/jax deg2rad

    const long long featUnits = (long long)B * 64;
    const long long stride = (long long)gridDim.x * 256;
    const long long tid0 = (long long)blockIdx.x * 256 + threadIdx.x;
    const f32x4 ZERO4 = {0.f, 0.f, 0.f, 0.f};

    for (long long u = tid0; u < featUnits; u += stride) {
        int b = (int)(u >> 6);                        // wave-uniform (aligned waves)
        int s = (int)(u & 63);                        // lane id
        float2 p = reinterpret_cast<const float2*>(ll)[b];   // broadcast load
        float rlat = p.x * DEG2RAD;                   // single f32 mul — bit-identical to ref
        float rlon = p.y * DEG2RAD;
        double ya = (double)rlat * QHI;               // revolutions at scale 2^0
        double yb = (double)rlon * QHI;
        double va = ldexp(ya, s);                     // exact power-of-two scale
        double vb = ldexp(yb, s);
        if (s == 31) { va = -va; vb = -vb; }          // int32 wrap: 2**31 -> -2^31 (select)
        double fa = va - floor(va);                   // frac -> revolutions in [0,1)
        double fb = vb - floor(vb);
        float ra = (float)fa, rb = (float)fb;
        f32x4 o;
        o.x = __builtin_amdgcn_sinf(ra);              // v_sin_f32: sin(2*pi*x)
        o.y = __builtin_amdgcn_cosf(ra);
        o.z = __builtin_amdgcn_sinf(rb);
        o.w = __builtin_amdgcn_cosf(rb);
        if (s >= 32) { o.x = 0.f; o.y = 1.f; o.z = 0.f; o.w = 1.f; }  // int32 wrap: 2**s==0 (select)
        __builtin_nontemporal_store(o, &out[u]);      // 1 KB contiguous per wave store
    }

    // zero tail: mask [B] + positions [2B] as f32, after B*64 float4s of features
    for (long long z = featUnits + tid0; z < n4; z += stride) {
        __builtin_nontemporal_store(ZERO4, &out[z]);
    }
}

__global__ void tail_zero_kernel(float* __restrict__ z, int n) {
    int t = threadIdx.x;
    if (t < n) z[t] = 0.f;
}

extern "C" void kernel_launch(void* const* d_in, const int* in_sizes, int n_in,
                              void* d_out, int out_size, void* d_ws, size_t ws_size,
                              hipStream_t stream) {
    const float* ll = (const float*)d_in[0];
    float* out = (float*)d_out;
    int B = in_sizes[0] / 2;

    long long n4 = (long long)out_size >> 2;
    posfeat_kernel<<<8192, 256, 0, stream>>>(ll, (f32x4*)out, B, n4);

    int tail = out_size & 3;
    if (tail) {
        tail_zero_kernel<<<1, 64, 0, stream>>>(out + ((long long)out_size - tail), tail);
    }
}

// Round 7
// 108.038 us; speedup vs baseline: 1.0482x; 1.0482x over previous
//
#include <hip/hip_runtime.h>

// AbsolutePositionExtractor: features[b, s*4+{0..3}] =
//   [sin(rad_lat*2^s), cos(rad_lat*2^s), sin(rad_lon*2^s), cos(rad_lon*2^s)]
// rad = fl32(deg*fl32(pi/180)); scale_s = int32(2**s): s=31 -> -2^31 (flip),
// s>=32 -> 0 -> (0,1,0,1). mask+positions = zeros.
//
// KEY STRUCTURE (R7): no VMEM loads inside the store loop. vmcnt decrements
// in-order, so a dependent global load each iteration forces vmcnt(0) = drain
// the store queue = serialize store[i] -> compute[i+1] (why R3/R5/R6 plateau
// at 5 TB/s vs the load-free fill kernel's 6.9). Stage y = rad/(2pi) as f64
// in LDS once per block; store loop reads via broadcast ds_read (lgkmcnt).
// Wave = one point x 64 scales -> every store is a contiguous 1 KB burst.

typedef float f32x4 __attribute__((ext_vector_type(4)));

#define PTS_PER_BLOCK 64   // 64 points * 64 f32x4 = 4 KB/iter * 16 iters per block
#define ZERO_BLOCKS   128  // first blocks zero mask+positions (overlapped)

__global__ __launch_bounds__(256) void posfeat_kernel(const float* __restrict__ ll,
                                                      f32x4* __restrict__ out,
                                                      int B, long long n4) {
    const double QHI = 0x1.45F306DC9C883p-3;      // fl64(1/(2*pi))
    const float DEG2RAD = 0.017453292519943295f;  // fl32(pi/180), matches np/jax deg2rad
    const long long featUnits = (long long)B * 64;

    if (blockIdx.x < ZERO_BLOCKS) {
        // zero region: mask [B] + positions [2B], after the feature float4s
        const f32x4 ZERO4 = {0.f, 0.f, 0.f, 0.f};
        const long long stride = (long long)ZERO_BLOCKS * 256;
        for (long long z = featUnits + (long long)blockIdx.x * 256 + threadIdx.x;
             z < n4; z += stride)
            __builtin_nontemporal_store(ZERO4, &out[z]);
        return;
    }

    __shared__ double yll[PTS_PER_BLOCK][2];
    const int fb = blockIdx.x - ZERO_BLOCKS;       // feature block id
    const int p0 = fb * PTS_PER_BLOCK;             // first point of this block
    const int t = threadIdx.x;

    if (t < PTS_PER_BLOCK) {                       // wave 0 stages 64 points
        int b = p0 + t;
        float2 p = (b < B) ? reinterpret_cast<const float2*>(ll)[b]
                           : make_float2(0.f, 0.f);
        float rlat = p.x * DEG2RAD;                // single f32 mul — bit-identical to ref
        float rlon = p.y * DEG2RAD;
        yll[t][0] = (double)rlat * QHI;            // revolutions at scale 2^0
        yll[t][1] = (double)rlon * QHI;
    }
    __syncthreads();

    const long long ubase = (long long)p0 * 64;
    const int s = t & 63;                          // lane id = scale
    #pragma unroll
    for (int i = 0; i < (PTS_PER_BLOCK * 64) / 256; ++i) {
        int idx = i * 256 + t;                     // unit within block
        long long u = ubase + idx;
        if (u >= featUnits) break;                 // (B-p0)*64 is a multiple of 64 -> wave-uniform
        int pl = idx >> 6;                         // local point, wave-uniform
        double ya = yll[pl][0], yb = yll[pl][1];   // broadcast ds_read_b128, conflict-free
        double va = ldexp(ya, s), vb = ldexp(yb, s);   // exact pow2 scale
        if (s == 31) { va = -va; vb = -vb; }       // int32 wrap: 2**31 -> -2^31 (select)
        double fa = va - floor(va), fb2 = vb - floor(vb);  // frac -> revolutions
        float ra = (float)fa, rb = (float)fb2;
        f32x4 o;
        o.x = __builtin_amdgcn_sinf(ra);           // v_sin_f32: sin(2*pi*x)
        o.y = __builtin_amdgcn_cosf(ra);
        o.z = __builtin_amdgcn_sinf(rb);
        o.w = __builtin_amdgcn_cosf(rb);
        if (s >= 32) { o = (f32x4){0.f, 1.f, 0.f, 1.f}; }  // int32 wrap: 2**s == 0 (select)
        __builtin_nontemporal_store(o, &out[u]);   // contiguous 1 KB per wave store
    }
}

__global__ void tail_zero_kernel(float* __restrict__ z, int n) {
    int t = threadIdx.x;
    if (t < n) z[t] = 0.f;
}

extern "C" void kernel_launch(void* const* d_in, const int* in_sizes, int n_in,
                              void* d_out, int out_size, void* d_ws, size_t ws_size,
                              hipStream_t stream) {
    const float* ll = (const float*)d_in[0];
    float* out = (float*)d_out;
    int B = in_sizes[0] / 2;

    long long n4 = (long long)out_size >> 2;
    int featBlocks = (B + PTS_PER_BLOCK - 1) / PTS_PER_BLOCK;
    posfeat_kernel<<<featBlocks + ZERO_BLOCKS, 256, 0, stream>>>(ll, (f32x4*)out, B, n4);

    int tail = out_size & 3;
    if (tail) {
        tail_zero_kernel<<<1, 64, 0, stream>>>(out + ((long long)out_size - tail), tail);
    }
}

// Round 8
// 100.926 us; speedup vs baseline: 1.1220x; 1.0705x over previous
//
#include <hip/hip_runtime.h>

// AbsolutePositionExtractor: features[b, s*4+{0..3}] =
//   [sin(rad_lat*2^s), cos(rad_lat*2^s), sin(rad_lon*2^s), cos(rad_lon*2^s)]
// rad = fl32(deg*fl32(pi/180)); scale_s = int32(2**s): s=31 -> -2^31 (negate),
// s>=32 -> 0 -> (0,1,0,1). mask+positions = zeros.
//
// R8: minimize compute per stored byte (R3..R7 rank by trig+f64 per byte, not
// by store pattern). Per point, stage yf = frac(rad/(2pi)) ONCE as 32.32
// fixed-point (hi,lo u32) in LDS. Per scale s<32: frac(y*2^s) = top32(Y<<s)
// = funnel shift + cvt_f32_u32 + mul 2^-32 (~6 cheap VALU ops, no f64).
// Scales 32..63 get constants directly (half the trig). NT stores.

typedef float f32x4 __attribute__((ext_vector_type(4)));

#define PTS 128          // points staged per block; block stores PTS KB
#define ZERO_BLOCKS 128  // dedicated blocks for mask+positions zeros

__global__ __launch_bounds__(256) void posfeat_kernel(const float* __restrict__ ll,
                                                      f32x4* __restrict__ out,
                                                      int B, long long n4) {
    const double QHI = 0x1.45F306DC9C883p-3;      // fl64(1/(2*pi))
    const float DEG2RAD = 0.017453292519943295f;  // fl32(pi/180), matches np/jax deg2rad
    const long long featUnits = (long long)B * 64;

    if (blockIdx.x < ZERO_BLOCKS) {               // mask [B] + positions [2B] = 0
        const f32x4 ZERO4 = {0.f, 0.f, 0.f, 0.f};
        const long long stride = (long long)ZERO_BLOCKS * 256;
        for (long long z = featUnits + (long long)blockIdx.x * 256 + threadIdx.x;
             z < n4; z += stride)
            __builtin_nontemporal_store(ZERO4, &out[z]);
        return;
    }

    __shared__ uint4 yfix[PTS];                   // (hi_lat, lo_lat, hi_lon, lo_lon)
    const int p0 = (blockIdx.x - ZERO_BLOCKS) * PTS;
    const int t = threadIdx.x;

    if (t < PTS) {                                // stage: f64 used ONLY here, once per point
        int b = p0 + t;
        float2 p = (b < B) ? reinterpret_cast<const float2*>(ll)[b]
                           : make_float2(0.f, 0.f);
        float rlat = p.x * DEG2RAD;               // single f32 mul — bit-identical to ref
        float rlon = p.y * DEG2RAD;
        double ya = (double)rlat * QHI; ya -= floor(ya);   // frac -> [0,1)
        double yb = (double)rlon * QHI; yb -= floor(yb);
        double sa = ya * 4294967296.0;
        unsigned ha = (unsigned)sa;
        unsigned la = (unsigned)((sa - (double)ha) * 4294967296.0);
        double sb = yb * 4294967296.0;
        unsigned hb = (unsigned)sb;
        unsigned lb = (unsigned)((sb - (double)hb) * 4294967296.0);
        yfix[t] = make_uint4(ha, la, hb, lb);
    }
    __syncthreads();

    const f32x4 CONST4 = {0.f, 1.f, 0.f, 1.f};
    const int s = t & 31;                         // scale 0..31 (32..63 are constants)
    const int po = t >> 5;                        // point-slot within iteration (0..7)
    const unsigned sh = (32 - s) & 31;

    #pragma unroll
    for (int i = 0; i < PTS / 8; ++i) {           // 16 iterations, 8 points each
        int pl = i * 8 + po;
        int b = p0 + pl;
        uint4 Y = yfix[pl];                       // broadcast ds_read_b128 (2 rows/wave)
        // frac(y * 2^s) as top 32 bits of (Y << s): funnel shift
        unsigned ra_u = (Y.x << s) | ((s == 0) ? 0u : (Y.y >> sh));
        unsigned rb_u = (Y.z << s) | ((s == 0) ? 0u : (Y.w >> sh));
        float ra = (float)ra_u * 0x1.0p-32f;      // revolutions in [0,1)
        float rb = (float)rb_u * 0x1.0p-32f;
        if (s == 31) { ra = -ra; rb = -rb; }      // int32 wrap: 2**31 -> -2^31
        f32x4 o;
        o.x = __builtin_amdgcn_sinf(ra);          // v_sin_f32: sin(2*pi*x)
        o.y = __builtin_amdgcn_cosf(ra);
        o.z = __builtin_amdgcn_sinf(rb);
        o.w = __builtin_amdgcn_cosf(rb);
        if (b < B) {
            long long base = ((long long)b << 6) + s;
            __builtin_nontemporal_store(o, &out[base]);           // scales 0..31
            __builtin_nontemporal_store(CONST4, &out[base + 32]); // scales 32..63
        }
    }
}

__global__ void tail_zero_kernel(float* __restrict__ z, int n) {
    int t = threadIdx.x;
    if (t < n) z[t] = 0.f;
}

extern "C" void kernel_launch(void* const* d_in, const int* in_sizes, int n_in,
                              void* d_out, int out_size, void* d_ws, size_t ws_size,
                              hipStream_t stream) {
    const float* ll = (const float*)d_in[0];
    float* out = (float*)d_out;
    int B = in_sizes[0] / 2;

    long long n4 = (long long)out_size >> 2;
    int featBlocks = (B + PTS - 1) / PTS;
    posfeat_kernel<<<featBlocks + ZERO_BLOCKS, 256, 0, stream>>>(ll, (f32x4*)out, B, n4);

    int tail = out_size & 3;
    if (tail) {
        tail_zero_kernel<<<1, 64, 0, stream>>>(out + ((long long)out_size - tail), tail);
    }
}

// Round 9
// 95.309 us; speedup vs baseline: 1.1881x; 1.0589x over previous
//
#include <hip/hip_runtime.h>

// AbsolutePositionExtractor: features[b, s*4+{0..3}] =
//   [sin(rad_lat*2^s), cos(rad_lat*2^s), sin(rad_lon*2^s), cos(rad_lon*2^s)]
// rad = fl32(deg*fl32(pi/180)); scale_s = int32(2**s): s=31 -> -2^31 (negate),
// s>=32 -> 0 -> (0,1,0,1). mask+positions = zeros.
//
// R9: persistent grid — 2048 blocks (8/CU, all resident, no dispatch tail, no
// block churn), each grid-strides over 256-point batches. R3..R8 showed the
// inner loop doesn't bind (trans pipe ~3%, VALU ~10% of budget); the residual
// vs the 75us BW floor is structural overhead. Loop body = R8's fixed-point:
// stage frac(rad/2pi) as 32.32 (hi,lo) in LDS once per point; per scale s<32
// frac(y*2^s) = top32(Y<<s) = funnel shift + cvt + mul. Scales 32..63 are
// constants (0,1,0,1). NT stores, every instr writes 64B-aligned full lines.

typedef float f32x4 __attribute__((ext_vector_type(4)));

#define PTS 256        // points staged per batch (4 KB LDS)
#define NBLK 2048      // 8 blocks/CU * 256 CUs — fully resident

__global__ __launch_bounds__(256) void posfeat_kernel(const float* __restrict__ ll,
                                                      f32x4* __restrict__ out,
                                                      int B, long long n4) {
    const double QHI = 0x1.45F306DC9C883p-3;      // fl64(1/(2*pi))
    const float DEG2RAD = 0.017453292519943295f;  // fl32(pi/180), matches np/jax deg2rad
    const long long featUnits = (long long)B * 64;
    const f32x4 CONST4 = {0.f, 1.f, 0.f, 1.f};
    const f32x4 ZERO4 = {0.f, 0.f, 0.f, 0.f};

    __shared__ uint4 yfix[PTS];                   // (hi_lat, lo_lat, hi_lon, lo_lon)
    const int t = threadIdx.x;
    const int nbatch = (B + PTS - 1) / PTS;

    const int s = t & 31;                         // scale 0..31 (32..63 are constants)
    const int po = t >> 5;                        // point-slot within iteration (0..7)
    const unsigned sh = (32 - s) & 31;

    for (int batch = blockIdx.x; batch < nbatch; batch += gridDim.x) {
        const int p0 = batch * PTS;
        {   // stage: all 256 threads, one point each; f64 used ONLY here
            int b = p0 + t;
            float2 p = (b < B) ? reinterpret_cast<const float2*>(ll)[b]
                               : make_float2(0.f, 0.f);
            float rlat = p.x * DEG2RAD;           // single f32 mul — bit-identical to ref
            float rlon = p.y * DEG2RAD;
            double ya = (double)rlat * QHI; ya -= floor(ya);   // frac -> [0,1)
            double yb = (double)rlon * QHI; yb -= floor(yb);
            double sa = ya * 4294967296.0;
            unsigned ha = (unsigned)sa;
            unsigned la = (unsigned)((sa - (double)ha) * 4294967296.0);
            double sb = yb * 4294967296.0;
            unsigned hb = (unsigned)sb;
            unsigned lb = (unsigned)((sb - (double)hb) * 4294967296.0);
            yfix[t] = make_uint4(ha, la, hb, lb);
        }
        __syncthreads();

        #pragma unroll 4
        for (int i = 0; i < PTS / 8; ++i) {       // 32 iterations, 8 points each
            int pl = i * 8 + po;
            int b = p0 + pl;
            uint4 Y = yfix[pl];                   // 2 distinct rows per wave (broadcast-ish)
            // frac(y * 2^s) = top 32 bits of (Y << s): funnel shift
            unsigned ra_u = (Y.x << s) | ((s == 0) ? 0u : (Y.y >> sh));
            unsigned rb_u = (Y.z << s) | ((s == 0) ? 0u : (Y.w >> sh));
            float ra = (float)ra_u * 0x1.0p-32f;  // revolutions in [0,1)
            float rb = (float)rb_u * 0x1.0p-32f;
            if (s == 31) { ra = -ra; rb = -rb; }  // int32 wrap: 2**31 -> -2^31
            f32x4 o;
            o.x = __builtin_amdgcn_sinf(ra);      // v_sin_f32: sin(2*pi*x)
            o.y = __builtin_amdgcn_cosf(ra);
            o.z = __builtin_amdgcn_sinf(rb);
            o.w = __builtin_amdgcn_cosf(rb);
            if (b < B) {
                long long base = ((long long)b << 6) + s;
                __builtin_nontemporal_store(o, &out[base]);           // scales 0..31
                __builtin_nontemporal_store(CONST4, &out[base + 32]); // scales 32..63
            }
        }
        __syncthreads();                          // LDS reuse guard for next batch
    }

    // zero epilogue: mask [B] + positions [2B] (6 MB), same dispatch
    const long long gstride = (long long)gridDim.x * 256;
    for (long long z = featUnits + (long long)blockIdx.x * 256 + t; z < n4; z += gstride)
        __builtin_nontemporal_store(ZERO4, &out[z]);
}

__global__ void tail_zero_kernel(float* __restrict__ z, int n) {
    int t = threadIdx.x;
    if (t < n) z[t] = 0.f;
}

extern "C" void kernel_launch(void* const* d_in, const int* in_sizes, int n_in,
                              void* d_out, int out_size, void* d_ws, size_t ws_size,
                              hipStream_t stream) {
    const float* ll = (const float*)d_in[0];
    float* out = (float*)d_out;
    int B = in_sizes[0] / 2;

    long long n4 = (long long)out_size >> 2;
    posfeat_kernel<<<NBLK, 256, 0, stream>>>(ll, (f32x4*)out, B, n4);

    int tail = out_size & 3;
    if (tail) {
        tail_zero_kernel<<<1, 64, 0, stream>>>(out + ((long long)out_size - tail), tail);
    }
}

// Round 10
// 92.532 us; speedup vs baseline: 1.2238x; 1.0300x over previous
//
#include <hip/hip_runtime.h>

// AbsolutePositionExtractor: features[b, s*4+{0..3}] =
//   [sin(rad_lat*2^s), cos(rad_lat*2^s), sin(rad_lon*2^s), cos(rad_lon*2^s)]
// rad = fl32(deg*fl32(pi/180)); scale_s = int32(2**s): s=31 -> -2^31 (negate),
// s>=32 -> 0 -> (0,1,0,1). mask+positions = zeros.
//
// R10: R9 persistent-grid structure, single change: NT -> PLAIN stores.
// NT was adopted untested in R3; the 87%-peak harness fill uses plain stores
// (L2 write-back aggregation). Everything else identical to R9 (95.3 us):
// 2048 resident blocks, 256-pt batch staged in LDS as 32.32 fixed-point,
// per-scale frac(y*2^s) = funnel shift + cvt + mul, scales 32..63 constant.

typedef float f32x4 __attribute__((ext_vector_type(4)));

#define PTS 256        // points staged per batch (4 KB LDS)
#define NBLK 2048      // 8 blocks/CU * 256 CUs — fully resident

__global__ __launch_bounds__(256) void posfeat_kernel(const float* __restrict__ ll,
                                                      f32x4* __restrict__ out,
                                                      int B, long long n4) {
    const double QHI = 0x1.45F306DC9C883p-3;      // fl64(1/(2*pi))
    const float DEG2RAD = 0.017453292519943295f;  // fl32(pi/180), matches np/jax deg2rad
    const long long featUnits = (long long)B * 64;
    const f32x4 CONST4 = {0.f, 1.f, 0.f, 1.f};
    const f32x4 ZERO4 = {0.f, 0.f, 0.f, 0.f};

    __shared__ uint4 yfix[PTS];                   // (hi_lat, lo_lat, hi_lon, lo_lon)
    const int t = threadIdx.x;
    const int nbatch = (B + PTS - 1) / PTS;

    const int s = t & 31;                         // scale 0..31 (32..63 are constants)
    const int po = t >> 5;                        // point-slot within iteration (0..7)
    const unsigned sh = (32 - s) & 31;

    for (int batch = blockIdx.x; batch < nbatch; batch += gridDim.x) {
        const int p0 = batch * PTS;
        {   // stage: all 256 threads, one point each; f64 used ONLY here
            int b = p0 + t;
            float2 p = (b < B) ? reinterpret_cast<const float2*>(ll)[b]
                               : make_float2(0.f, 0.f);
            float rlat = p.x * DEG2RAD;           // single f32 mul — bit-identical to ref
            float rlon = p.y * DEG2RAD;
            double ya = (double)rlat * QHI; ya -= floor(ya);   // frac -> [0,1)
            double yb = (double)rlon * QHI; yb -= floor(yb);
            double sa = ya * 4294967296.0;
            unsigned ha = (unsigned)sa;
            unsigned la = (unsigned)((sa - (double)ha) * 4294967296.0);
            double sb = yb * 4294967296.0;
            unsigned hb = (unsigned)sb;
            unsigned lb = (unsigned)((sb - (double)hb) * 4294967296.0);
            yfix[t] = make_uint4(ha, la, hb, lb);
        }
        __syncthreads();

        #pragma unroll 4
        for (int i = 0; i < PTS / 8; ++i) {       // 32 iterations, 8 points each
            int pl = i * 8 + po;
            int b = p0 + pl;
            uint4 Y = yfix[pl];                   // 2 distinct rows per wave (broadcast)
            // frac(y * 2^s) = top 32 bits of (Y << s): funnel shift
            unsigned ra_u = (Y.x << s) | ((s == 0) ? 0u : (Y.y >> sh));
            unsigned rb_u = (Y.z << s) | ((s == 0) ? 0u : (Y.w >> sh));
            float ra = (float)ra_u * 0x1.0p-32f;  // revolutions in [0,1)
            float rb = (float)rb_u * 0x1.0p-32f;
            if (s == 31) { ra = -ra; rb = -rb; }  // int32 wrap: 2**31 -> -2^31
            f32x4 o;
            o.x = __builtin_amdgcn_sinf(ra);      // v_sin_f32: sin(2*pi*x)
            o.y = __builtin_amdgcn_cosf(ra);
            o.z = __builtin_amdgcn_sinf(rb);
            o.w = __builtin_amdgcn_cosf(rb);
            if (b < B) {
                long long base = ((long long)b << 6) + s;
                out[base] = o;                    // scales 0..31 (plain store)
                out[base + 32] = CONST4;          // scales 32..63 (plain store)
            }
        }
        __syncthreads();                          // LDS reuse guard for next batch
    }

    // zero epilogue: mask [B] + positions [2B] (6 MB), same dispatch
    const long long gstride = (long long)gridDim.x * 256;
    for (long long z = featUnits + (long long)blockIdx.x * 256 + t; z < n4; z += gstride)
        out[z] = ZERO4;
}

__global__ void tail_zero_kernel(float* __restrict__ z, int n) {
    int t = threadIdx.x;
    if (t < n) z[t] = 0.f;
}

extern "C" void kernel_launch(void* const* d_in, const int* in_sizes, int n_in,
                              void* d_out, int out_size, void* d_ws, size_t ws_size,
                              hipStream_t stream) {
    const float* ll = (const float*)d_in[0];
    float* out = (float*)d_out;
    int B = in_sizes[0] / 2;

    long long n4 = (long long)out_size >> 2;
    posfeat_kernel<<<NBLK, 256, 0, stream>>>(ll, (f32x4*)out, B, n4);

    int tail = out_size & 3;
    if (tail) {
        tail_zero_kernel<<<1, 64, 0, stream>>>(out + ((long long)out_size - tail), tail);
    }
}